// Round 8
// baseline (256.156 us; speedup 1.0000x reference)
//
#include <hip/hip_runtime.h>
#include <hip/hip_bf16.h>
#include <math.h>

// NoisyTopkRouter round 14: contiguous panel streaming (kill the K-windows).
// Post-mortems: only the DRAM address stream has ever moved this kernel
// (r12 -8us; everything else neutral). Every round so far staged K-windows:
// each wave-instr = 64 lanes x 16B at 4KB stride = 64 DRAM lines / instr.
// The harness fills stream contiguous at 6.9 TB/s on this same chip; we
// never issued a contiguous stream. r8 showed L3-served reads equally slow
// -> degradation follows the PATTERN, not the tier.
// Fix: M_TILE=16 -> block panel = 16 rows x 4KB = 64KB CONTIGUOUS. Stage it
// once (16 coalesced dwordx4/thread; wave-instr = 1KB contiguous), cvt to
// bf16 hi/lo frag-order LDS, 1 barrier, then barrier-free K=1024 MFMA sweep
// (32 chunks, 2-deep B reg prefetch). 2 blocks/CU -> cross-block overlap of
// stage and sweep. Chunk order 0..31 = same summation order as r6 ->
// bitwise-identical numerics (absmax 0.00390625).
// LDS layout: subblock (c,g) stride 136 elems (128 + 8 pad): staging writes
// (16-lane group: 16 distinct 2-word slots = conflict-free) and frag reads
// (16-lane group: 2 accesses/bank) both clean; 16B alignment preserved.
// Kill-switch: if a fill-like stream still runs ~1 TB/s, pattern theory is
// falsified -> platform read-path cap -> declare roofline next round.

#define T_TOKENS 32768
#define D_MODEL  1024
#define NE       64
#define NCOL     128
#define M_TILE   16
#define NCHUNK   32
#define SUBS     136       // subblock stride in elems: 16 rows * 8 + 8 pad
#define CS_LD    68
#define OUT_IDX_BASE ((size_t)T_TOKENS * NE)
#define W_ELEMS  (NCOL * D_MODEL)

typedef short  bf16x8  __attribute__((ext_vector_type(8)));
typedef float  floatx4 __attribute__((ext_vector_type(4)));

__device__ __forceinline__ float softplus_f(float x) {
    return fmaxf(x, 0.f) + log1pf(expf(-fabsf(x)));
}

// 8 floats -> packed bf16 hi + lo. RNE hi, exact residual, RNE lo.
// (prepack only; numerics identical to rounds 2-13.)
__device__ __forceinline__ void cvt8(const float4 a, const float4 b,
                                     int4* hi, int4* lo) {
    float v[8] = {a.x, a.y, a.z, a.w, b.x, b.y, b.z, b.w};
    int hw[4], lw[4];
    #pragma unroll
    for (int p = 0; p < 4; ++p) {
        float2 f2 = make_float2(v[2 * p], v[2 * p + 1]);
        __hip_bfloat162 h2 = __float22bfloat162_rn(f2);
        int u; __builtin_memcpy(&u, &h2, 4);
        float h0 = __uint_as_float(((unsigned)u) << 16);
        float h1 = __uint_as_float(((unsigned)u) & 0xFFFF0000u);
        float2 l2 = make_float2(v[2 * p] - h0, v[2 * p + 1] - h1);
        __hip_bfloat162 L2 = __float22bfloat162_rn(l2);
        int ul; __builtin_memcpy(&ul, &L2, 4);
        hw[p] = u; lw[p] = ul;
    }
    *hi = make_int4(hw[0], hw[1], hw[2], hw[3]);
    *lo = make_int4(lw[0], lw[1], lw[2], lw[3]);
}

// 4 floats -> 4 bf16 hi (int2) + 4 bf16 lo (int2). Same pairings as cvt8
// on j-halves {0..3}/{4..7} -> numerically identical results.
__device__ __forceinline__ void cvt4(const float4 a, int2* hi, int2* lo) {
    float v[4] = {a.x, a.y, a.z, a.w};
    int hw[2], lw[2];
    #pragma unroll
    for (int p = 0; p < 2; ++p) {
        float2 f2 = make_float2(v[2 * p], v[2 * p + 1]);
        __hip_bfloat162 h2 = __float22bfloat162_rn(f2);
        int u; __builtin_memcpy(&u, &h2, 4);
        float h0 = __uint_as_float(((unsigned)u) << 16);
        float h1 = __uint_as_float(((unsigned)u) & 0xFFFF0000u);
        float2 l2 = make_float2(v[2 * p] - h0, v[2 * p + 1] - h1);
        __hip_bfloat162 L2 = __float22bfloat162_rn(l2);
        int ul; __builtin_memcpy(&ul, &L2, 4);
        hw[p] = u; lw[p] = ul;
    }
    *hi = make_int2(hw[0], hw[1]);
    *lo = make_int2(lw[0], lw[1]);
}

// ---------------- prepack: W -> hi/lo bf16 in B-frag order ----------------
// elem index = ((ntile*128 + kgrp)*16 + n16)*8 + j ; value = W[ntile*16+n16][kgrp*8+j]
__global__ __launch_bounds__(256) void prepack_w(
    const float* __restrict__ Wr, const float* __restrict__ Wn,
    short* __restrict__ Bh, short* __restrict__ Bl)
{
    int g   = blockIdx.x * 256 + threadIdx.x;
    int n   = g & 15;
    int kg  = (g >> 4) & 127;
    int t2  = g >> 11;
    int col = t2 * 16 + n;
    const float* src = (col < NE ? Wr + (size_t)col * D_MODEL
                                 : Wn + (size_t)(col - NE) * D_MODEL) + kg * 8;
    float4 a = *(const float4*)src;
    float4 b = *(const float4*)(src + 4);
    int4 hi, lo;
    cvt8(a, b, &hi, &lo);
    *(int4*)(Bh + (size_t)g * 8) = hi;
    *(int4*)(Bl + (size_t)g * 8) = lo;
}

// ---------------- main fused kernel ----------------
__global__ __launch_bounds__(256, 2) void router_mfma(
    const float* __restrict__ A,
    const float* __restrict__ noise,
    const float* __restrict__ br,
    const float* __restrict__ bn,
    const short* __restrict__ Bh,
    const short* __restrict__ Bl,
    float* __restrict__ out)
{
    // full-K bf16 hi/lo panel, frag-order with padded subblocks.
    __shared__ __align__(16) short Ah[NCHUNK * 4 * SUBS];   // 34816 B
    __shared__ __align__(16) short Al[NCHUNK * 4 * SUBS];   // 34816 B
    __shared__ float Ns[M_TILE * CS_LD];                    // noise slice
    __shared__ float s_p1[M_TILE], s_p2[M_TILE];
    __shared__ int   s_e1[M_TILE], s_e2[M_TILE];
    float* Cs = reinterpret_cast<float*>(&Ah[0]);           // alias, post-sweep

    const int tid  = threadIdx.x;
    const int lane = tid & 63;
    const int wid  = tid >> 6;   // wave: route ntile wid, noise ntile wid+4
    const int n16  = lane & 15;
    const int quad = lane >> 4;
    const size_t blk = blockIdx.x;
    const int m0   = (int)blk * M_TILE;

    // ---- staging: CONTIGUOUS 64KB panel read ----
    // instr i: wave w lanes cover bytes [w*1024, w*1024+1KB) of row i ->
    // perfectly coalesced; block = sequential 64KB span of A.
    const float* panel = A + blk * (size_t)(M_TILE * D_MODEL);
    float4 f[16];
    #pragma unroll
    for (int i = 0; i < 16; ++i)
        f[i] = *(const float4*)(panel + i * D_MODEL + tid * 4);
    // noise slice: 4KB contiguous, 1 float4/thread
    float4 nzf = *(const float4*)(noise + blk * (size_t)(M_TILE * NE) + tid * 4);

    // B chunk 0/1 prefetch (independent of LDS; overlaps staging drain)
    const short* pBhR = Bh + ((size_t)(wid * 128 + quad) * 16 + n16) * 8;
    const short* pBlR = Bl + ((size_t)(wid * 128 + quad) * 16 + n16) * 8;
    const short* pBhN = Bh + ((size_t)((4 + wid) * 128 + quad) * 16 + n16) * 8;
    const short* pBlN = Bl + ((size_t)((4 + wid) * 128 + quad) * 16 + n16) * 8;
    bf16x8 b0hR = *(const bf16x8*)(pBhR);
    bf16x8 b0lR = *(const bf16x8*)(pBlR);
    bf16x8 b0hN = *(const bf16x8*)(pBhN);
    bf16x8 b0lN = *(const bf16x8*)(pBlN);
    bf16x8 b1hR = *(const bf16x8*)(pBhR + 512);
    bf16x8 b1lR = *(const bf16x8*)(pBlR + 512);
    bf16x8 b1hN = *(const bf16x8*)(pBhN + 512);
    bf16x8 b1lN = *(const bf16x8*)(pBlN + 512);

    // cvt + frag-order write. Thread t owns k = 4t..4t+3 of every row:
    // subblock sb = (c= t>>3)*4 + (g=(t>>1)&3), j-half = (t&1)*4.
    // 16-lane write group -> 16 distinct 2-word slots: conflict-free.
    {
        const int sb    = (tid >> 3) * 4 + ((tid >> 1) & 3);
        const int dbase = sb * SUBS + (tid & 1) * 4;
        #pragma unroll
        for (int i = 0; i < 16; ++i) {
            int2 hi, lo;
            cvt4(f[i], &hi, &lo);
            *(int2*)&Ah[dbase + i * 8] = hi;
            *(int2*)&Al[dbase + i * 8] = lo;
        }
        *(float4*)&Ns[(tid >> 4) * CS_LD + (tid & 15) * 4] = nzf;
    }
    __syncthreads();

    // ---- barrier-free K=1024 MFMA sweep (32 chunks, 2-deep B prefetch) ----
    floatx4 acc0 = (floatx4)0.f, acc1 = (floatx4)0.f;
    const int aOff = quad * SUBS + n16 * 8;
    #pragma unroll
    for (int c = 0; c < NCHUNK; ++c) {
        bf16x8 b2hR, b2lR, b2hN, b2lN;
        if (c + 2 < NCHUNK) {
            const int o = (c + 2) * 512;
            b2hR = *(const bf16x8*)(pBhR + o);
            b2lR = *(const bf16x8*)(pBlR + o);
            b2hN = *(const bf16x8*)(pBhN + o);
            b2lN = *(const bf16x8*)(pBlN + o);
        }
        // frag read: 16-lane group = 2 accesses/bank (conflict-free)
        bf16x8 ah = *(const bf16x8*)&Ah[c * 4 * SUBS + aOff];
        bf16x8 al = *(const bf16x8*)&Al[c * 4 * SUBS + aOff];
        acc0 = __builtin_amdgcn_mfma_f32_16x16x32_bf16(ah, b0hR, acc0, 0, 0, 0);
        acc0 = __builtin_amdgcn_mfma_f32_16x16x32_bf16(ah, b0lR, acc0, 0, 0, 0);
        acc0 = __builtin_amdgcn_mfma_f32_16x16x32_bf16(al, b0hR, acc0, 0, 0, 0);
        acc1 = __builtin_amdgcn_mfma_f32_16x16x32_bf16(ah, b0hN, acc1, 0, 0, 0);
        acc1 = __builtin_amdgcn_mfma_f32_16x16x32_bf16(ah, b0lN, acc1, 0, 0, 0);
        acc1 = __builtin_amdgcn_mfma_f32_16x16x32_bf16(al, b0hN, acc1, 0, 0, 0);
        // rotate B (named regs, no dynamic indexing)
        b0hR = b1hR; b0lR = b1lR; b0hN = b1hN; b0lN = b1lN;
        b1hR = b2hR; b1lR = b2lR; b1hN = b2hN; b1lN = b2lN;
    }
    __syncthreads();   // all Ah/Al reads retired before Cs alias writes

    // ---- lane-local fuse: noisy = route + noise * softplus(noise_logit) ----
    {
        const int e = wid * 16 + n16;
        float brv = br[e], bnv = bn[e];
        #pragma unroll
        for (int rr = 0; rr < 4; ++rr) {
            int t = quad * 4 + rr;
            float nz    = Ns[t * CS_LD + e];
            float route = acc0[rr] + brv;
            float nl    = acc1[rr] + bnv;
            Cs[t * CS_LD + e] = fmaf(nz, softplus_f(nl), route);
        }
    }
    __syncthreads();

    // ---- top-2 + softmax (one thread per token; in-order scan = stable ties)
    if (tid < M_TILE) {
        const int t = tid;
        float v1 = -INFINITY, v2 = -INFINITY;
        int e1 = 0, e2 = 0;
        #pragma unroll
        for (int e4 = 0; e4 < 16; ++e4) {
            float4 q = *(const float4*)&Cs[t * CS_LD + e4 * 4];
            float qa[4] = {q.x, q.y, q.z, q.w};
            #pragma unroll
            for (int c = 0; c < 4; ++c) {
                float v = qa[c];
                int e = e4 * 4 + c;
                if (v > v1) { v2 = v1; e2 = e1; v1 = v; e1 = e; }
                else if (v > v2) { v2 = v; e2 = e; }
            }
        }
        float ex = expf(v2 - v1);
        float denom = 1.f + ex;
        s_p1[t] = 1.f / denom;
        s_p2[t] = ex / denom;
        s_e1[t] = e1;
        s_e2[t] = e2;
        float2 iv = make_float2((float)e1, (float)e2);
        *(float2*)(out + OUT_IDX_BASE + (size_t)(m0 + t) * 2) = iv;
    }
    __syncthreads();

    // ---- coalesced scatter of router_output [16 tokens x 64 experts] ----
    {
        int t  = tid >> 4;
        int e0 = (tid & 15) * 4;
        float p1 = s_p1[t], p2 = s_p2[t];
        int   e1 = s_e1[t], e2 = s_e2[t];
        float4 v;
        v.x = (e0 + 0 == e1) ? p1 : ((e0 + 0 == e2) ? p2 : 0.f);
        v.y = (e0 + 1 == e1) ? p1 : ((e0 + 1 == e2) ? p2 : 0.f);
        v.z = (e0 + 2 == e1) ? p1 : ((e0 + 2 == e2) ? p2 : 0.f);
        v.w = (e0 + 3 == e1) ? p1 : ((e0 + 3 == e2) ? p2 : 0.f);
        *(float4*)(out + (size_t)(m0 + t) * NE + e0) = v;
    }
}

extern "C" void kernel_launch(void* const* d_in, const int* in_sizes, int n_in,
                              void* d_out, int out_size, void* d_ws, size_t ws_size,
                              hipStream_t stream) {
    const float* A     = (const float*)d_in[0];
    const float* noise = (const float*)d_in[1];
    const float* Wr    = (const float*)d_in[2];
    const float* br    = (const float*)d_in[3];
    const float* Wn    = (const float*)d_in[4];
    const float* bn    = (const float*)d_in[5];
    float* out = (float*)d_out;

    short* Bh = (short*)d_ws;
    short* Bl = Bh + W_ELEMS;

    prepack_w<<<dim3(W_ELEMS / 8 / 256), dim3(256), 0, stream>>>(Wr, Wn, Bh, Bl);
    router_mfma<<<dim3(T_TOKENS / M_TILE), dim3(256), 0, stream>>>(A, noise, br, bn, Bh, Bl, out);
}

// Round 9
// 252.573 us; speedup vs baseline: 1.0142x; 1.0142x over previous
//
#include <hip/hip_runtime.h>
#include <hip/hip_bf16.h>
#include <math.h>

// NoisyTopkRouter round 15: r12 verbatim + non-temporal cache hints.
// r14 post-mortem: contiguous-A test was confounded (M=16 -> 4x grid -> B
// L2 traffic 268MB->1.07GB + 2.1M bank conflicts); also retracting r8's
// "L3-resident same-speed" claim (those rows had FETCH=NaN, WRITE-only).
// r12 (K-phase rotation, phase = blk&15) remains the ONLY win. This round:
// revert to r12 exactly, add ONE change: __builtin_nontemporal_load on the
// read-once A/noise streams and nontemporal_store on the write-once outputs.
// Theory: the 134MB/iter A stream sweeps each 4MB XCD-L2 ~4x/iter, evicting
// the hot 512KB B workspace that supplies 268MB of per-wave frag reads at
// only depth-1..2 prefetch; B falling out of L2 exposes latency at the
// next-chunk MFMA dependency. nt keeps B resident. B loads stay default.
// Numerics identical to r12 (hints don't change values).

#define T_TOKENS 32768
#define D_MODEL  1024
#define NE       64
#define NCOL     128
#define M_TILE   64
#define KSTAGE   64
#define NSTAGE   16
#define CS_LD    68
#define OUT_IDX_BASE ((size_t)T_TOKENS * NE)
#define W_ELEMS  (NCOL * D_MODEL)

typedef short  bf16x8  __attribute__((ext_vector_type(8)));
typedef float  floatx4 __attribute__((ext_vector_type(4)));
typedef float  f32x4   __attribute__((ext_vector_type(4)));
typedef float  f32x2   __attribute__((ext_vector_type(2)));

__device__ __forceinline__ float4 ldnt4(const float* p) {
    f32x4 v = __builtin_nontemporal_load((const f32x4*)p);
    return make_float4(v.x, v.y, v.z, v.w);
}
__device__ __forceinline__ void stnt4(float* p, float4 v) {
    f32x4 u; u.x = v.x; u.y = v.y; u.z = v.z; u.w = v.w;
    __builtin_nontemporal_store(u, (f32x4*)p);
}
__device__ __forceinline__ void stnt2(float* p, float a, float b) {
    f32x2 u; u.x = a; u.y = b;
    __builtin_nontemporal_store(u, (f32x2*)p);
}

__device__ __forceinline__ float softplus_f(float x) {
    return fmaxf(x, 0.f) + log1pf(expf(-fabsf(x)));
}

// 8 floats -> packed bf16 hi (int4) + bf16 lo (int4). RNE hi, exact residual,
// RNE lo — numerically identical to rounds 2-14.
__device__ __forceinline__ void cvt8(const float4 a, const float4 b,
                                     int4* hi, int4* lo) {
    float v[8] = {a.x, a.y, a.z, a.w, b.x, b.y, b.z, b.w};
    int hw[4], lw[4];
    #pragma unroll
    for (int p = 0; p < 4; ++p) {
        float2 f2 = make_float2(v[2 * p], v[2 * p + 1]);
        __hip_bfloat162 h2 = __float22bfloat162_rn(f2);
        int u; __builtin_memcpy(&u, &h2, 4);
        float h0 = __uint_as_float(((unsigned)u) << 16);
        float h1 = __uint_as_float(((unsigned)u) & 0xFFFF0000u);
        float2 l2 = make_float2(v[2 * p] - h0, v[2 * p + 1] - h1);
        __hip_bfloat162 L2 = __float22bfloat162_rn(l2);
        int ul; __builtin_memcpy(&ul, &L2, 4);
        hw[p] = u; lw[p] = ul;
    }
    *hi = make_int4(hw[0], hw[1], hw[2], hw[3]);
    *lo = make_int4(lw[0], lw[1], lw[2], lw[3]);
}

// ---------------- prepack: W -> hi/lo bf16 in B-frag order ----------------
// elem index = ((ntile*128 + kgrp)*16 + n16)*8 + j ; value = W[ntile*16+n16][kgrp*8+j]
__global__ __launch_bounds__(256) void prepack_w(
    const float* __restrict__ Wr, const float* __restrict__ Wn,
    short* __restrict__ Bh, short* __restrict__ Bl)
{
    int g   = blockIdx.x * 256 + threadIdx.x;
    int n   = g & 15;
    int kg  = (g >> 4) & 127;
    int t2  = g >> 11;
    int col = t2 * 16 + n;
    const float* src = (col < NE ? Wr + (size_t)col * D_MODEL
                                 : Wn + (size_t)(col - NE) * D_MODEL) + kg * 8;
    float4 a = *(const float4*)src;
    float4 b = *(const float4*)(src + 4);
    int4 hi, lo;
    cvt8(a, b, &hi, &lo);
    *(int4*)(Bh + (size_t)g * 8) = hi;
    *(int4*)(Bl + (size_t)g * 8) = lo;
}

// ---------------- main fused kernel ----------------
__global__ __launch_bounds__(256, 2) void router_mfma(
    const float* __restrict__ A,
    const float* __restrict__ noise,
    const float* __restrict__ br,
    const float* __restrict__ bn,
    const short* __restrict__ Bh,
    const short* __restrict__ Bl,
    float* __restrict__ out)
{
    // frag-order staged A, K=64 per stage (2 MFMA chunks), double-buffered.
    __shared__ __align__(16) short Ah[2][M_TILE * KSTAGE];
    __shared__ __align__(16) short Al[2][M_TILE * KSTAGE];
    __shared__ float Cs[M_TILE * CS_LD];
    __shared__ float s_p1[M_TILE], s_p2[M_TILE];
    __shared__ int   s_e1[M_TILE], s_e2[M_TILE];

    const int tid  = threadIdx.x;
    const int lane = tid & 63;
    const int wid  = tid >> 6;   // wave: route ntile wid, noise ntile wid+4
    const int n16  = lane & 15;
    const int quad = lane >> 4;
    const int m0   = blockIdx.x * M_TILE;

    // per-block K-phase: block processes windows (s + phase) mod 16
    const int phase = blockIdx.x & 15;

    // staging: row r = tid&63, kgrp g = tid>>6 (same proven conflict-free
    // pattern as r6/r11/r12; SQ_LDS_BANK_CONFLICT == 0).
    const int r  = tid & 63;
    const int g  = tid >> 6;
    const float* pA = A + (size_t)(m0 + r) * D_MODEL + g * 8;
    const int sBase = (g * M_TILE + r) * 8;            // chunk0 dest
    // chunk1 dest = sBase + 2048

    const short* pBhR = Bh + ((size_t)(wid * 128 + quad) * 16 + n16) * 8;
    const short* pBlR = Bl + ((size_t)(wid * 128 + quad) * 16 + n16) * 8;
    const short* pBhN = Bh + ((size_t)((4 + wid) * 128 + quad) * 16 + n16) * 8;
    const short* pBlN = Bl + ((size_t)((4 + wid) * 128 + quad) * 16 + n16) * 8;

    floatx4 acc[4][2];   // [m-frag][route/noise]
    #pragma unroll
    for (int i = 0; i < 4; ++i) { acc[i][0] = (floatx4)0.f; acc[i][1] = (floatx4)0.f; }

    // ---- prologue: stage window w0 into buf 0; raw A for w1; B chunk0(w0) ----
    const int w0 = phase;
    const int w1 = (phase + 1) & 15;
    {
        const float* q = pA + w0 * KSTAGE;
        float4 a0 = ldnt4(q);
        float4 a1 = ldnt4(q + 4);
        float4 a2 = ldnt4(q + 32);
        float4 a3 = ldnt4(q + 36);
        int4 hi, lo;
        cvt8(a0, a1, &hi, &lo);
        *(int4*)&Ah[0][sBase] = hi;
        *(int4*)&Al[0][sBase] = lo;
        cvt8(a2, a3, &hi, &lo);
        *(int4*)&Ah[0][sBase + 2048] = hi;
        *(int4*)&Al[0][sBase + 2048] = lo;
    }
    float4 nx0a = ldnt4(pA + w1 * KSTAGE);
    float4 nx0b = ldnt4(pA + w1 * KSTAGE + 4);
    float4 nx1a = ldnt4(pA + w1 * KSTAGE + 32);
    float4 nx1b = ldnt4(pA + w1 * KSTAGE + 36);
    bf16x8 c0hR = *(const bf16x8*)(pBhR + w0 * 1024);
    bf16x8 c0lR = *(const bf16x8*)(pBlR + w0 * 1024);
    bf16x8 c0hN = *(const bf16x8*)(pBhN + w0 * 1024);
    bf16x8 c0lN = *(const bf16x8*)(pBlN + w0 * 1024);
    __syncthreads();

    float nz[4][4];   // noise prefetch (filled at stage NSTAGE-3)

    #pragma unroll 2
    for (int s = 0; s < NSTAGE; ++s) {
        const int cur = s & 1, nxt = cur ^ 1;
        const int ps  = (s + phase) & 15;    // physical K-window this stage

        // raw A for stage s+2 (window (ps+2) mod 16)
        float4 f0a, f0b, f1a, f1b;
        if (s + 2 < NSTAGE) {
            const float* q = pA + ((ps + 2) & 15) * KSTAGE;
            f0a = ldnt4(q);
            f0b = ldnt4(q + 4);
            f1a = ldnt4(q + 32);
            f1b = ldnt4(q + 36);
        }

        // B chunk1 of this window (used ~400+ cyc later, L2-hit covered)
        const int ob1 = (ps * 2 + 1) * 512;
        bf16x8 c1hR = *(const bf16x8*)(pBhR + ob1);
        bf16x8 c1lR = *(const bf16x8*)(pBlR + ob1);
        bf16x8 c1hN = *(const bf16x8*)(pBhN + ob1);
        bf16x8 c1lN = *(const bf16x8*)(pBlN + ob1);
        // B chunk0 of next window
        bf16x8 n0hR, n0lR, n0hN, n0lN;
        if (s + 1 < NSTAGE) {
            const int ob0 = ((ps + 1) & 15) * 1024;
            n0hR = *(const bf16x8*)(pBhR + ob0);
            n0lR = *(const bf16x8*)(pBlR + ob0);
            n0hN = *(const bf16x8*)(pBhN + ob0);
            n0lN = *(const bf16x8*)(pBlN + ob0);
        }

        // noise prefetch: 16 scalar nt loads, ~3 stages before use
        if (s == NSTAGE - 3) {
            const int e = wid * 16 + n16;
            #pragma unroll
            for (int mf = 0; mf < 4; ++mf)
                #pragma unroll
                for (int rr = 0; rr < 4; ++rr)
                    nz[mf][rr] = __builtin_nontemporal_load(
                        noise + (size_t)(m0 + mf * 16 + quad * 4 + rr) * NE + e);
        }

        // ---- chunk 0: frags + 24 MFMAs ----
        #pragma unroll
        for (int mf = 0; mf < 4; ++mf) {
            const int gi = (quad * M_TILE + mf * 16 + n16) * 8;
            bf16x8 afh = *(const bf16x8*)&Ah[cur][gi];
            bf16x8 afl = *(const bf16x8*)&Al[cur][gi];
            acc[mf][0] = __builtin_amdgcn_mfma_f32_16x16x32_bf16(afh, c0hR, acc[mf][0], 0, 0, 0);
            acc[mf][0] = __builtin_amdgcn_mfma_f32_16x16x32_bf16(afh, c0lR, acc[mf][0], 0, 0, 0);
            acc[mf][0] = __builtin_amdgcn_mfma_f32_16x16x32_bf16(afl, c0hR, acc[mf][0], 0, 0, 0);
            acc[mf][1] = __builtin_amdgcn_mfma_f32_16x16x32_bf16(afh, c0hN, acc[mf][1], 0, 0, 0);
            acc[mf][1] = __builtin_amdgcn_mfma_f32_16x16x32_bf16(afh, c0lN, acc[mf][1], 0, 0, 0);
            acc[mf][1] = __builtin_amdgcn_mfma_f32_16x16x32_bf16(afl, c0hN, acc[mf][1], 0, 0, 0);
        }
        // ---- chunk 1: frags + 24 MFMAs ----
        #pragma unroll
        for (int mf = 0; mf < 4; ++mf) {
            const int gi = ((4 + quad) * M_TILE + mf * 16 + n16) * 8;
            bf16x8 afh = *(const bf16x8*)&Ah[cur][gi];
            bf16x8 afl = *(const bf16x8*)&Al[cur][gi];
            acc[mf][0] = __builtin_amdgcn_mfma_f32_16x16x32_bf16(afh, c1hR, acc[mf][0], 0, 0, 0);
            acc[mf][0] = __builtin_amdgcn_mfma_f32_16x16x32_bf16(afh, c1lR, acc[mf][0], 0, 0, 0);
            acc[mf][0] = __builtin_amdgcn_mfma_f32_16x16x32_bf16(afl, c1hR, acc[mf][0], 0, 0, 0);
            acc[mf][1] = __builtin_amdgcn_mfma_f32_16x16x32_bf16(afh, c1hN, acc[mf][1], 0, 0, 0);
            acc[mf][1] = __builtin_amdgcn_mfma_f32_16x16x32_bf16(afh, c1lN, acc[mf][1], 0, 0, 0);
            acc[mf][1] = __builtin_amdgcn_mfma_f32_16x16x32_bf16(afl, c1hN, acc[mf][1], 0, 0, 0);
        }

        // stage s+1 (raw regs loaded last iteration)
        if (s + 1 < NSTAGE) {
            int4 hi, lo;
            cvt8(nx0a, nx0b, &hi, &lo);
            *(int4*)&Ah[nxt][sBase] = hi;
            *(int4*)&Al[nxt][sBase] = lo;
            cvt8(nx1a, nx1b, &hi, &lo);
            *(int4*)&Ah[nxt][sBase + 2048] = hi;
            *(int4*)&Al[nxt][sBase + 2048] = lo;
        }

        __syncthreads();

        nx0a = f0a; nx0b = f0b; nx1a = f1a; nx1b = f1b;
        c0hR = n0hR; c0lR = n0lR; c0hN = n0hN; c0lN = n0lN;
    }

    // ---- lane-local fuse: noisy = route + noise * softplus(noise_logit) ----
    // D layout: col = lane&15 (expert within ntile), row = quad*4 + rr
    {
        const int e = wid * 16 + n16;
        float brv = br[e], bnv = bn[e];
        #pragma unroll
        for (int mf = 0; mf < 4; ++mf)
            #pragma unroll
            for (int rr = 0; rr < 4; ++rr) {
                int t = mf * 16 + quad * 4 + rr;
                float route = acc[mf][0][rr] + brv;
                float nl    = acc[mf][1][rr] + bnv;
                Cs[t * CS_LD + e] = fmaf(nz[mf][rr], softplus_f(nl), route);
            }
    }
    __syncthreads();

    // ---- top-2 + softmax: 4 waves x 16 tokens (in-order scan = stable ties)
    if (lane < 16) {
        const int t = wid * 16 + lane;
        float v1 = -INFINITY, v2 = -INFINITY;
        int e1 = 0, e2 = 0;
        #pragma unroll
        for (int e4 = 0; e4 < 16; ++e4) {
            float4 q = *(const float4*)&Cs[t * CS_LD + e4 * 4];
            float qa[4] = {q.x, q.y, q.z, q.w};
            #pragma unroll
            for (int c = 0; c < 4; ++c) {
                float v = qa[c];
                int e = e4 * 4 + c;
                if (v > v1) { v2 = v1; e2 = e1; v1 = v; e1 = e; }
                else if (v > v2) { v2 = v; e2 = e; }
            }
        }
        float ex = expf(v2 - v1);
        float denom = 1.f + ex;
        s_p1[t] = 1.f / denom;
        s_p2[t] = ex / denom;
        s_e1[t] = e1;
        s_e2[t] = e2;
        stnt2(out + OUT_IDX_BASE + (size_t)(m0 + t) * 2, (float)e1, (float)e2);
    }
    __syncthreads();

    // ---- coalesced scatter of router_output [64 tokens x 64 experts] ----
    #pragma unroll
    for (int i = 0; i < 4; ++i) {
        int gi = i * 256 + tid;       // 0..1023 float4s
        int t  = gi >> 4;
        int e0 = (gi & 15) * 4;
        float p1 = s_p1[t], p2 = s_p2[t];
        int   e1 = s_e1[t], e2 = s_e2[t];
        float4 v;
        v.x = (e0 + 0 == e1) ? p1 : ((e0 + 0 == e2) ? p2 : 0.f);
        v.y = (e0 + 1 == e1) ? p1 : ((e0 + 1 == e2) ? p2 : 0.f);
        v.z = (e0 + 2 == e1) ? p1 : ((e0 + 2 == e2) ? p2 : 0.f);
        v.w = (e0 + 3 == e1) ? p1 : ((e0 + 3 == e2) ? p2 : 0.f);
        stnt4(out + (size_t)(m0 + t) * NE + e0, v);
    }
}

extern "C" void kernel_launch(void* const* d_in, const int* in_sizes, int n_in,
                              void* d_out, int out_size, void* d_ws, size_t ws_size,
                              hipStream_t stream) {
    const float* A     = (const float*)d_in[0];
    const float* noise = (const float*)d_in[1];
    const float* Wr    = (const float*)d_in[2];
    const float* br    = (const float*)d_in[3];
    const float* Wn    = (const float*)d_in[4];
    const float* bn    = (const float*)d_in[5];
    float* out = (float*)d_out;

    short* Bh = (short*)d_ws;
    short* Bl = Bh + W_ELEMS;

    prepack_w<<<dim3(W_ELEMS / 8 / 256), dim3(256), 0, stream>>>(Wr, Wn, Bh, Bl);
    router_mfma<<<dim3(T_TOKENS / M_TILE), dim3(256), 0, stream>>>(A, noise, br, bn, Bh, Bl, out);
}